// Round 1
// baseline (19292.278 us; speedup 1.0000x reference)
//
#include <hip/hip_runtime.h>
#include <hip/hip_bf16.h>
#include <cstdint>
#include <cstddef>

// ---------------- problem constants ----------------
#define NH    64
#define NB    384
#define EDIM  1024
#define PAIRS (NH*NB)   // 24576
#define SPA   36

// ---------------- dtype config (flip these two lines if harness dtypes differ) ----------------
using in_t  = float;            // reference builds all tensors as float32
using out_t = float;            // reference output is float32
using sb_t  = __hip_bfloat16;   // internal big s-buffers (precision: fine at 2% threshold)

static __device__ __forceinline__ float cvt(float x){ return x; }
static __device__ __forceinline__ float cvt(__hip_bfloat16 x){ return __bfloat162float(x); }
static __device__ __forceinline__ void stv(float* p, float v){ *p = v; }
static __device__ __forceinline__ void stv(__hip_bfloat16* p, float v){ *p = __float2bfloat16(v); }

// ---------------- bias/constant pool layout (floats) ----------------
#define POOL_BB1   0
#define POOL_BB2   1024
#define POOL_BS1   2048
#define POOL_BS2   2176
#define POOL_BS3   2432
#define POOL_AB1   3456
#define POOL_AB2   4480
#define POOL_GB1   5504
#define POOL_GB2   6528
#define POOL_SB1   7552
#define POOL_SB2   8576
#define POOL_OB1   9600
#define POOL_OB2   10624
#define POOL_AB3S  11648
#define POOL_GB3S  12672
#define POOL_SB3S  13696
#define POOL_OB3S  14720
#define POOL_GFEAT 15744
#define POOL_TOTAL 16000

// ============================================================================
// Generic tiled GEMM.
//   C[r, z*N + n] = epi( sum_c Aelem(r,c) * B[z][c,n] )
// MODE 0: Aelem = S[r*ldsS + c]                (plain)
// MODE 1: Aelem = relu( (U[(r/NB)*ldu + c] + V[(r%NB)*ldv + c]) * S[r*ldsS + c] )
//         (U / V may be null; ldu==0 broadcasts one row)
// Batched over blockIdx.z with B += z*strideB, output cols offset z*N, bias[z*N+n].
// ============================================================================
template<int MODE, typename TS, typename TC>
__global__ __launch_bounds__(256)
void gemm_kernel(int M, int N, int K,
                 const float* __restrict__ U, int ldu,
                 const float* __restrict__ V, int ldv,
                 const TS* __restrict__ S, int ldsS,
                 const in_t* __restrict__ B, int ldb, long long strideB,
                 const float* __restrict__ bias,
                 TC* __restrict__ C, int ldc, int reluOut)
{
  __shared__ float As[16][65];   // [kk][m], padded vs bank conflicts
  __shared__ float Bs[16][68];   // [kk][n]
  const int z  = blockIdx.z;
  const in_t* Bz = B + (long long)z * strideB;
  const int m0 = blockIdx.x * 64;
  const int n0 = blockIdx.y * 64;
  const int tid = threadIdx.x;
  const int tx = tid & 15;   // column group
  const int ty = tid >> 4;   // row group

  float acc[4][4];
  #pragma unroll
  for (int i=0;i<4;++i)
    #pragma unroll
    for (int j=0;j<4;++j) acc[i][j]=0.f;

  const int kTiles = (K + 15) >> 4;
  for (int kt=0; kt<kTiles; ++kt) {
    const int k0 = kt << 4;
    // ---- load A tile (64 rows x 16 k), 4 elems/thread, coalesced in k ----
    #pragma unroll
    for (int q=0;q<4;++q) {
      const int m = ty + 16*q;
      const int p = m0 + m;
      const int c = k0 + tx;
      float v = 0.f;
      if (p < M && c < K) {
        if (MODE == 0) {
          v = cvt(S[(size_t)p*ldsS + c]);
        } else {
          float a = 0.f;
          if (U) a += U[(size_t)(p/NB)*ldu + c];
          if (V) a += V[(size_t)(p%NB)*ldv + c];
          v = fmaxf(a * cvt(S[(size_t)p*ldsS + c]), 0.f);
        }
      }
      As[tx][m] = v;
    }
    // ---- load B tile (16 k x 64 n), coalesced in n ----
    {
      const int n = tid & 63;
      #pragma unroll
      for (int q=0;q<4;++q) {
        const int kk = (tid >> 6) + 4*q;
        const int gk = k0 + kk;
        const int gn = n0 + n;
        float v = 0.f;
        if (gk < K && gn < N) v = cvt(Bz[(size_t)gk*ldb + gn]);
        Bs[kk][n] = v;
      }
    }
    __syncthreads();
    #pragma unroll
    for (int kk=0; kk<16; ++kk) {
      float a[4], b[4];
      #pragma unroll
      for (int i=0;i<4;++i) a[i] = As[kk][ty + 16*i];
      #pragma unroll
      for (int j=0;j<4;++j) b[j] = Bs[kk][tx + 16*j];
      #pragma unroll
      for (int i=0;i<4;++i)
        #pragma unroll
        for (int j=0;j<4;++j) acc[i][j] += a[i]*b[j];
    }
    __syncthreads();
  }
  // ---- epilogue ----
  #pragma unroll
  for (int i=0;i<4;++i) {
    const int r = m0 + ty + 16*i;
    if (r >= M) continue;
    #pragma unroll
    for (int j=0;j<4;++j) {
      const int nn = n0 + tx + 16*j;
      if (nn >= N) continue;
      const int ccol = z*N + nn;
      float v = acc[i][j];
      if (bias) v += bias[ccol];
      if (reluOut) v = fmaxf(v, 0.f);
      stv(&C[(size_t)r*ldc + ccol], v);
    }
  }
}

// ============================================================================
// prep: copy 13 bias vectors into fp32 pool + 4 sums over k of (16,1024) b3's
// ============================================================================
struct Prep17 { const in_t* p[17]; };

__global__ __launch_bounds__(256)
void prep_kernel(Prep17 a, float* __restrict__ pool)
{
  const int len[17] = {1024,1024,128,256,1024,1024,1024,1024,1024,1024,1024,1024,1024,
                       1024,1024,1024,1024};
  const int off[17] = {POOL_BB1,POOL_BB2,POOL_BS1,POOL_BS2,POOL_BS3,POOL_AB1,POOL_AB2,
                       POOL_GB1,POOL_GB2,POOL_SB1,POOL_SB2,POOL_OB1,POOL_OB2,
                       POOL_AB3S,POOL_GB3S,POOL_SB3S,POOL_OB3S};
  const int j = blockIdx.x;
  const in_t* src = a.p[j];
  const int L = len[j], o = off[j];
  for (int i = threadIdx.x; i < L; i += blockDim.x) {
    if (j < 13) {
      pool[o+i] = cvt(src[i]);
    } else {
      float s = 0.f;
      for (int k=0;k<16;++k) s += cvt(src[k*1024 + i]);
      pool[o+i] = s;
    }
  }
}

// gfeat[c] = mean over 7x7 of features3[0,c,:,:]
__global__ __launch_bounds__(64)
void gfeat_kernel(const in_t* __restrict__ f3, float* __restrict__ g)
{
  const int c = blockIdx.x;
  const int t = threadIdx.x;
  float s = (t < 49) ? cvt(f3[c*49 + t]) : 0.f;
  #pragma unroll
  for (int o=32;o>0;o>>=1) s += __shfl_down(s, o, 64);
  if (t == 0) g[c] = s * (1.0f/49.0f);
}

__global__ void copy_kernel(const float* __restrict__ s, float* __restrict__ d, int n)
{
  int i = blockIdx.x*256 + threadIdx.x;
  if (i < n) d[i] = s[i];
}

// adj[p] = badj + sum_r relu(tmp[p,r] + Ab3s[r]) * Wadj[r]
__global__ __launch_bounds__(256)
void adj_kernel(const float* __restrict__ tmp, const float* __restrict__ ab3s,
                const in_t* __restrict__ Wadj, const in_t* __restrict__ badj,
                float* __restrict__ adj)
{
  __shared__ float red[256];
  const int p = blockIdx.x, t = threadIdx.x;
  float a = 0.f;
  for (int r=t; r<1024; r+=256)
    a += fmaxf(tmp[(size_t)p*1024 + r] + ab3s[r], 0.f) * cvt(Wadj[r]);
  red[t]=a; __syncthreads();
  for (int s=128;s>0;s>>=1){ if(t<s) red[t]+=red[t+s]; __syncthreads(); }
  if (t==0) adj[p] = red[0] + cvt(badj[0]);
}

// block-wide reductions, blockDim.x == 1024
static __device__ __forceinline__ float bsum(float v, float* red){
  const int t = threadIdx.x;
  red[t]=v; __syncthreads();
  for (int s=512;s>0;s>>=1){ if(t<s) red[t]+=red[t+s]; __syncthreads(); }
  float r = red[0]; __syncthreads();
  return r;
}
static __device__ __forceinline__ float bmax(float v, float* red){
  const int t = threadIdx.x;
  red[t]=v; __syncthreads();
  for (int s=512;s>0;s>>=1){ if(t<s) red[t]=fmaxf(red[t],red[t+s]); __syncthreads(); }
  float r = red[0]; __syncthreads();
  return r;
}

// h[hh,:] = LN( h + relu( Ob3s + sum_n softmax(adj[hh,:])[n] * mo[hh*NB+n, :] ) )
__global__ __launch_bounds__(1024)
void h_update_kernel(const float* __restrict__ adj, const float* __restrict__ mo,
                     const float* __restrict__ ob3s, const in_t* __restrict__ g,
                     const in_t* __restrict__ b, float* __restrict__ h)
{
  __shared__ float red[1024];
  __shared__ float w[NB];
  const int hh = blockIdx.x, t = threadIdx.x;
  float av = (t < NB) ? adj[hh*NB + t] : -1e30f;
  float mx = bmax(av, red);
  float e = (t < NB) ? expf(av - mx) : 0.f;
  if (t < NB) w[t] = e;
  float sm = bsum(e, red);
  const float inv = 1.0f / sm;
  float acc = 0.f;
  const float* mop = mo + (size_t)hh*NB*1024 + t;
  for (int n=0; n<NB; ++n) acc += w[n] * mop[(size_t)n*1024];
  acc *= inv;
  float val = h[(size_t)hh*1024 + t] + fmaxf(acc + ob3s[t], 0.f);
  float mean = bsum(val, red) * (1.0f/1024.0f);
  float d = val - mean;
  float var = bsum(d*d, red) * (1.0f/1024.0f);
  float y = d * rsqrtf(var + 1e-5f) * cvt(g[t]) + cvt(b[t]);
  h[(size_t)hh*1024 + t] = y;
}

// o[n,:] = LN( o + relu( Sb3s + sum_h softmax(adj[:,n])[h] * ms[h*NB+n, :] ) )
__global__ __launch_bounds__(1024)
void o_update_kernel(const float* __restrict__ adj, const float* __restrict__ ms,
                     const float* __restrict__ sb3s, const in_t* __restrict__ g,
                     const in_t* __restrict__ b, float* __restrict__ o)
{
  __shared__ float red[1024];
  __shared__ float w[NH];
  const int n = blockIdx.x, t = threadIdx.x;
  float av = (t < NH) ? adj[t*NB + n] : -1e30f;
  float mx = bmax(av, red);
  float e = (t < NH) ? expf(av - mx) : 0.f;
  if (t < NH) w[t] = e;
  float sm = bsum(e, red);
  const float inv = 1.0f / sm;
  float acc = 0.f;
  const float* msp = ms + (size_t)n*1024 + t;
  for (int hh=0; hh<NH; ++hh) acc += w[hh] * msp[(size_t)hh*NB*1024];
  acc *= inv;
  float val = o[(size_t)n*1024 + t] + fmaxf(acc + sb3s[t], 0.f);
  float mean = bsum(val, red) * (1.0f/1024.0f);
  float d = val - mean;
  float var = bsum(d*d, red) * (1.0f/1024.0f);
  float y = d * rsqrtf(var + 1e-5f) * cvt(g[t]) + cvt(b[t]);
  o[(size_t)n*1024 + t] = y;
}

// ---------------- host-side launcher ----------------
template<int MODE, typename TS, typename TC>
static inline void launch_gemm(hipStream_t st, int M, int N, int K,
    const float* U, int ldu, const float* V, int ldv,
    const TS* S, int ldsS, const in_t* B, int ldb, long long strideB, int nz,
    const float* bias, TC* C, int ldc, int relu)
{
  dim3 grid((unsigned)((M+63)/64), (unsigned)((N+63)/64), (unsigned)nz);
  hipLaunchKernelGGL((gemm_kernel<MODE,TS,TC>), grid, dim3(256), 0, st,
                     M,N,K,U,ldu,V,ldv,S,ldsS,B,ldb,strideB,bias,C,ldc,relu);
}

extern "C" void kernel_launch(void* const* d_in, const int* in_sizes, int n_in,
                              void* d_out, int out_size, void* d_ws, size_t ws_size,
                              hipStream_t stream)
{
  (void)in_sizes; (void)n_in; (void)out_size; (void)ws_size;

  const in_t* box  = (const in_t*)d_in[0];
  const in_t* spat = (const in_t*)d_in[1];
  const in_t* f3   = (const in_t*)d_in[2];
  const in_t* Wb1  = (const in_t*)d_in[3];
  const in_t* Wb2  = (const in_t*)d_in[5];
  const in_t* Ws1  = (const in_t*)d_in[7];
  const in_t* Ws2  = (const in_t*)d_in[9];
  const in_t* Ws3  = (const in_t*)d_in[11];
  const in_t* Wadj = (const in_t*)d_in[13];
  const in_t* badj = (const in_t*)d_in[14];
  const in_t* gh   = (const in_t*)d_in[15];
  const in_t* bh   = (const in_t*)d_in[16];
  const in_t* go   = (const in_t*)d_in[17];
  const in_t* bo   = (const in_t*)d_in[18];
  const in_t* A1   = (const in_t*)d_in[19];
  const in_t* A2   = (const in_t*)d_in[21];
  const in_t* A3   = (const in_t*)d_in[23];
  const in_t* G1   = (const in_t*)d_in[25];
  const in_t* G2   = (const in_t*)d_in[27];
  const in_t* G3   = (const in_t*)d_in[29];
  const in_t* S1   = (const in_t*)d_in[31];
  const in_t* S2   = (const in_t*)d_in[33];
  const in_t* S3   = (const in_t*)d_in[35];
  const in_t* O1   = (const in_t*)d_in[37];
  const in_t* O2   = (const in_t*)d_in[39];
  const in_t* O3   = (const in_t*)d_in[41];
  out_t* out = (out_t*)d_out;

  // ---- workspace carve-up (~450 MB) ----
  char* wsb = (char*)d_ws;
  size_t off = 0;
  auto alloc = [&](size_t bytes)->void* {
    void* p = wsb + off; off += (bytes + 255) & ~(size_t)255; return p;
  };
  float* pool   = (float*)alloc((size_t)POOL_TOTAL*4);
  float* encMid = (float*)alloc((size_t)NB*EDIM*4);
  float* oB     = (float*)alloc((size_t)NB*EDIM*4);
  float* hB     = (float*)alloc((size_t)NH*EDIM*4);
  float* sp1    = (float*)alloc((size_t)PAIRS*128*4);
  float* sp2    = (float*)alloc((size_t)PAIRS*256*4);
  float* spF    = (float*)alloc((size_t)PAIRS*EDIM*4);
  float* tmp    = (float*)alloc((size_t)PAIRS*EDIM*4);
  float* ahA    = (float*)alloc((size_t)NH*EDIM*4);
  float* aoA    = (float*)alloc((size_t)NB*EDIM*4);
  float* aoO    = (float*)alloc((size_t)NB*EDIM*4);
  float* ahS    = (float*)alloc((size_t)NH*EDIM*4);
  float* aGv    = (float*)alloc((size_t)EDIM*4);
  float* adj    = (float*)alloc((size_t)PAIRS*4);
  sb_t* sA  = (sb_t*)alloc((size_t)PAIRS*EDIM*2);
  sb_t* sO  = (sb_t*)alloc((size_t)PAIRS*EDIM*2);
  sb_t* sH  = (sb_t*)alloc((size_t)PAIRS*EDIM*2);
  sb_t* sGb = (sb_t*)alloc((size_t)PAIRS*EDIM*2);

  // ---- prep: bias pool + b3 sums + gfeat ----
  Prep17 pp;
  const int prepIdx[17] = {4,6,8,10,12,20,22,26,28,32,34,38,40,24,30,36,42};
  for (int i=0;i<17;++i) pp.p[i] = (const in_t*)d_in[prepIdx[i]];
  hipLaunchKernelGGL(prep_kernel, dim3(17), dim3(256), 0, stream, pp, pool);
  hipLaunchKernelGGL(gfeat_kernel, dim3(256), dim3(64), 0, stream, f3, pool + POOL_GFEAT);

  // ---- enc = relu(relu(box@Wb1+bb1)@Wb2+bb2); h = enc[:64], o = enc ----
  launch_gemm<0,float,float>(stream, NB, EDIM, 12544, nullptr,0,nullptr,0,
      box, 12544, Wb1, EDIM, 0, 1, pool+POOL_BB1, encMid, EDIM, 1);
  launch_gemm<0,float,float>(stream, NB, EDIM, EDIM, nullptr,0,nullptr,0,
      encMid, EDIM, Wb2, EDIM, 0, 1, pool+POOL_BB2, oB, EDIM, 1);
  hipLaunchKernelGGL(copy_kernel, dim3(NH*EDIM/256), dim3(256), 0, stream,
      oB, hB, NH*EDIM);

  // ---- spatial MLP: 36 -> 128 -> 256 -> 1024 ----
  launch_gemm<0,float,float>(stream, PAIRS, 128, SPA, nullptr,0,nullptr,0,
      spat, SPA, Ws1, 128, 0, 1, pool+POOL_BS1, sp1, 128, 1);
  launch_gemm<0,float,float>(stream, PAIRS, 256, 128, nullptr,0,nullptr,0,
      sp1, 128, Ws2, 256, 0, 1, pool+POOL_BS2, sp2, 256, 1);
  launch_gemm<0,float,float>(stream, PAIRS, EDIM, 256, nullptr,0,nullptr,0,
      sp2, 256, Ws3, EDIM, 0, 1, pool+POOL_BS3, spF, EDIM, 1);

  // ---- loop-invariant s-operands: sp @ {A2,O2,S2,G2} + b2  (batched z=16, N=64) ----
  launch_gemm<0,float,sb_t>(stream, PAIRS, 64, EDIM, nullptr,0,nullptr,0,
      spF, EDIM, A2, 64, 65536, 16, pool+POOL_AB2, sA, EDIM, 0);
  launch_gemm<0,float,sb_t>(stream, PAIRS, 64, EDIM, nullptr,0,nullptr,0,
      spF, EDIM, O2, 64, 65536, 16, pool+POOL_OB2, sO, EDIM, 0);
  launch_gemm<0,float,sb_t>(stream, PAIRS, 64, EDIM, nullptr,0,nullptr,0,
      spF, EDIM, S2, 64, 65536, 16, pool+POOL_SB2, sH, EDIM, 0);
  launch_gemm<0,float,sb_t>(stream, PAIRS, 64, EDIM, nullptr,0,nullptr,0,
      spF, EDIM, G2, 64, 65536, 16, pool+POOL_GB2, sGb, EDIM, 0);

  // ---- aG = gfeat @ G1 + Gb1 (single row) ----
  launch_gemm<0,float,float>(stream, 1, 64, 256, nullptr,0,nullptr,0,
      pool+POOL_GFEAT, 256, G1, 64, 16384, 16, pool+POOL_GB1, aGv, EDIM, 0);

  // ---- 2 message-passing iterations ----
  for (int it=0; it<2; ++it) {
    // a-parts for mbf(pair_app(h,o), A*)
    launch_gemm<0,float,float>(stream, NH, 64, EDIM, nullptr,0,nullptr,0,
        hB, EDIM, A1, 64, 131072, 16, pool+POOL_AB1, ahA, EDIM, 0);
    launch_gemm<0,float,float>(stream, NB, 64, EDIM, nullptr,0,nullptr,0,
        oB, EDIM, A1 + (size_t)1024*64, 64, 131072, 16, nullptr, aoA, EDIM, 0);
    // tmp = sum_c relu((ahA+aoA)*sA) @ A3   (raw, pre-bias/relu)
    launch_gemm<1,sb_t,float>(stream, PAIRS, EDIM, EDIM, ahA, EDIM, aoA, EDIM,
        sA, EDIM, A3, EDIM, 0, 1, nullptr, tmp, EDIM, 0);
    hipLaunchKernelGGL(adj_kernel, dim3(PAIRS), dim3(256), 0, stream,
        tmp, pool+POOL_AB3S, Wadj, badj, adj);
    // O path -> h update
    launch_gemm<0,float,float>(stream, NB, 64, EDIM, nullptr,0,nullptr,0,
        oB, EDIM, O1, 64, 65536, 16, pool+POOL_OB1, aoO, EDIM, 0);
    launch_gemm<1,sb_t,float>(stream, PAIRS, EDIM, EDIM, nullptr,0, aoO, EDIM,
        sO, EDIM, O3, EDIM, 0, 1, nullptr, tmp, EDIM, 0);
    hipLaunchKernelGGL(h_update_kernel, dim3(NH), dim3(1024), 0, stream,
        adj, tmp, pool+POOL_OB3S, gh, bh, hB);
    // S path -> o update
    launch_gemm<0,float,float>(stream, NH, 64, EDIM, nullptr,0,nullptr,0,
        hB, EDIM, S1, 64, 65536, 16, pool+POOL_SB1, ahS, EDIM, 0);
    launch_gemm<1,sb_t,float>(stream, PAIRS, EDIM, EDIM, ahS, EDIM, nullptr,0,
        sH, EDIM, S3, EDIM, 0, 1, nullptr, tmp, EDIM, 0);
    hipLaunchKernelGGL(o_update_kernel, dim3(NB), dim3(1024), 0, stream,
        adj, tmp, pool+POOL_SB3S, go, bo, oB);
  }

  // ---- final heads ----
  launch_gemm<0,float,float>(stream, NH, 64, EDIM, nullptr,0,nullptr,0,
      hB, EDIM, A1, 64, 131072, 16, pool+POOL_AB1, ahA, EDIM, 0);
  launch_gemm<0,float,float>(stream, NB, 64, EDIM, nullptr,0,nullptr,0,
      oB, EDIM, A1 + (size_t)1024*64, 64, 131072, 16, nullptr, aoA, EDIM, 0);
  // attn -> out[:, 0:1024]
  launch_gemm<1,sb_t,out_t>(stream, PAIRS, EDIM, EDIM, ahA, EDIM, aoA, EDIM,
      sA, EDIM, A3, EDIM, 0, 1, pool+POOL_AB3S, out, 2048, 1);
  // attn_g -> out[:, 1024:2048]  (a-part is one broadcast row: ldu = 0)
  launch_gemm<1,sb_t,out_t>(stream, PAIRS, EDIM, EDIM, aGv, 0, nullptr, 0,
      sGb, EDIM, G3, EDIM, 0, 1, pool+POOL_GB3S, out + EDIM, 2048, 1);
}

// Round 2
// 2440.009 us; speedup vs baseline: 7.9066x; 7.9066x over previous
//
#include <hip/hip_runtime.h>
#include <hip/hip_bf16.h>
#include <cstdint>
#include <cstddef>

// ---------------- problem constants ----------------
#define NH    64
#define NB    384
#define EDIM  1024
#define PAIRS (NH*NB)   // 24576
#define SPA   36

using in_t  = float;            // reference builds all tensors as float32
using out_t = float;            // reference output is float32
using sb_t  = __hip_bfloat16;   // internal bf16 storage

typedef short bf16x8 __attribute__((ext_vector_type(8)));  // 8 bf16 (4 VGPRs)
typedef float f32x4  __attribute__((ext_vector_type(4)));  // 4 fp32 acc

static __device__ __forceinline__ float cvt(float x){ return x; }
static __device__ __forceinline__ float cvt(__hip_bfloat16 x){ return __bfloat162float(x); }
static __device__ __forceinline__ void stv(float* p, float v){ *p = v; }
static __device__ __forceinline__ void stv(__hip_bfloat16* p, float v){ *p = __float2bfloat16(v); }

static __device__ __forceinline__ float b2f(unsigned short u){
  union { unsigned int i; float f; } x; x.i = ((unsigned int)u)<<16; return x.f;
}
static __device__ __forceinline__ unsigned short f2b(float f){
  union { float f; unsigned int i; } x; x.f = f;
  unsigned int r = x.i + 0x7fffu + ((x.i>>16)&1u);
  return (unsigned short)(r>>16);
}

typedef const __attribute__((address_space(1))) void* as1_t;
typedef __attribute__((address_space(3))) void* as3_t;
static __device__ __forceinline__ void gl_lds16(const void* g, void* l){
  __builtin_amdgcn_global_load_lds((as1_t)g, (as3_t)l, 16, 0, 0);
}

// ---------------- bias/constant pool layout (floats) ----------------
#define POOL_BB1   0
#define POOL_BB2   1024
#define POOL_BS1   2048
#define POOL_BS2   2176
#define POOL_BS3   2432
#define POOL_AB1   3456
#define POOL_AB2   4480
#define POOL_GB1   5504
#define POOL_GB2   6528
#define POOL_SB1   7552
#define POOL_SB2   8576
#define POOL_OB1   9600
#define POOL_OB2   10624
#define POOL_AB3S  11648
#define POOL_GB3S  12672
#define POOL_SB3S  13696
#define POOL_OB3S  14720
#define POOL_GFEAT 15744
#define POOL_TOTAL 16000

// ============================================================================
// MFMA bf16 GEMM: C[row, coff+col] = epi( A[MxK] @ Bt[NxK]^T )
// Requirements: M%128==0, N%128==0, K%32==0, 16B-aligned pointers.
// 256 threads = 4 waves (2x2), 128x128 block tile, BK=32, m97-style staging.
// ============================================================================
template<int RELU, typename TC>
__global__ __launch_bounds__(256)
void gemm_mfma(int M, int N, int K, int ldb,
               const sb_t* __restrict__ A,
               const sb_t* __restrict__ Bt,
               const float* __restrict__ bias,
               TC* __restrict__ C, int ldc, int coff)
{
  __shared__ alignas(16) short lA[128*32];
  __shared__ alignas(16) short lB[128*32];
  const int tid = threadIdx.x;
  const int w = tid >> 6, l = tid & 63;
  const int m0 = blockIdx.x * 128, n0 = blockIdx.y * 128;
  const int wr = w >> 1, wc = w & 1;   // wave tile: rows wr*64, cols wc*64

  // staging: each wave fills rows w*32 .. w*32+31 of lA and lB (2 insts each)
  const int srow = w*32 + (l>>2);        // +16 for the second inst
  const int scol = (l&3)*8;
  const sb_t* gA = A  + (size_t)(m0 + srow)*(size_t)K   + scol;
  const sb_t* gB = Bt + (size_t)(n0 + srow)*(size_t)ldb + scol;
  short* lAw = &lA[(w*32)*32];
  short* lBw = &lB[(w*32)*32];

  f32x4 acc[4][4];
  const f32x4 zz = {0.f,0.f,0.f,0.f};
  #pragma unroll
  for (int i=0;i<4;++i)
    #pragma unroll
    for (int j=0;j<4;++j) acc[i][j] = zz;

  const int fr  = l & 15;          // fragment row (A) / row-n (B)
  const int fko = (l >> 4) * 8;    // fragment k offset

  for (int k0 = 0; k0 < K; k0 += 32) {
    gl_lds16(gA + k0,                    lAw);
    gl_lds16(gA + k0 + (size_t)16*K,     lAw + 16*32);
    gl_lds16(gB + k0,                    lBw);
    gl_lds16(gB + k0 + (size_t)16*ldb,   lBw + 16*32);
    __syncthreads();   // drains vmcnt, publishes LDS
    bf16x8 af[4], bfv[4];
    #pragma unroll
    for (int i=0;i<4;++i)
      af[i]  = *(const bf16x8*)&lA[(wr*64 + i*16 + fr)*32 + fko];
    #pragma unroll
    for (int j=0;j<4;++j)
      bfv[j] = *(const bf16x8*)&lB[(wc*64 + j*16 + fr)*32 + fko];
    #pragma unroll
    for (int i=0;i<4;++i)
      #pragma unroll
      for (int j=0;j<4;++j)
        acc[i][j] = __builtin_amdgcn_mfma_f32_16x16x32_bf16(af[i], bfv[j], acc[i][j], 0, 0, 0);
    __syncthreads();
  }

  // epilogue: C/D layout col = lane&15, row = (lane>>4)*4 + reg (m89/m91-verified)
  const int cn = l & 15;
  const int cr = (l >> 4) * 4;
  #pragma unroll
  for (int j=0;j<4;++j) {
    const int col = n0 + wc*64 + j*16 + cn;
    const float bv = bias ? bias[col] : 0.f;
    #pragma unroll
    for (int i=0;i<4;++i) {
      #pragma unroll
      for (int r=0;r<4;++r) {
        const int row = m0 + wr*64 + i*16 + cr + r;
        float v = acc[i][j][r] + bv;
        if (RELU) v = fmaxf(v, 0.f);
        stv(&C[(size_t)row*ldc + coff + col], v);
      }
    }
  }
}

// ============================================================================
// fp32 VALU GEMM (kept for tiny/odd shapes: spatial 36->128, gfeat@G1)
// ============================================================================
template<int MODE, typename TS, typename TC>
__global__ __launch_bounds__(256)
void gemm_kernel(int M, int N, int K,
                 const float* __restrict__ U, int ldu,
                 const float* __restrict__ V, int ldv,
                 const TS* __restrict__ S, int ldsS,
                 const in_t* __restrict__ B, int ldb, long long strideB,
                 const float* __restrict__ bias,
                 TC* __restrict__ C, int ldc, int reluOut)
{
  __shared__ float As[16][65];
  __shared__ float Bs[16][68];
  const int z  = blockIdx.z;
  const in_t* Bz = B + (long long)z * strideB;
  const int m0 = blockIdx.x * 64;
  const int n0 = blockIdx.y * 64;
  const int tid = threadIdx.x;
  const int tx = tid & 15;
  const int ty = tid >> 4;

  float acc[4][4];
  #pragma unroll
  for (int i=0;i<4;++i)
    #pragma unroll
    for (int j=0;j<4;++j) acc[i][j]=0.f;

  const int kTiles = (K + 15) >> 4;
  for (int kt=0; kt<kTiles; ++kt) {
    const int k0 = kt << 4;
    #pragma unroll
    for (int q=0;q<4;++q) {
      const int m = ty + 16*q;
      const int p = m0 + m;
      const int c = k0 + tx;
      float v = 0.f;
      if (p < M && c < K) {
        if (MODE == 0) {
          v = cvt(S[(size_t)p*ldsS + c]);
        } else {
          float a = 0.f;
          if (U) a += U[(size_t)(p/NB)*ldu + c];
          if (V) a += V[(size_t)(p%NB)*ldv + c];
          v = fmaxf(a * cvt(S[(size_t)p*ldsS + c]), 0.f);
        }
      }
      As[tx][m] = v;
    }
    {
      const int n = tid & 63;
      #pragma unroll
      for (int q=0;q<4;++q) {
        const int kk = (tid >> 6) + 4*q;
        const int gk = k0 + kk;
        const int gn = n0 + n;
        float v = 0.f;
        if (gk < K && gn < N) v = cvt(Bz[(size_t)gk*ldb + gn]);
        Bs[kk][n] = v;
      }
    }
    __syncthreads();
    #pragma unroll
    for (int kk=0; kk<16; ++kk) {
      float a[4], b[4];
      #pragma unroll
      for (int i=0;i<4;++i) a[i] = As[kk][ty + 16*i];
      #pragma unroll
      for (int j=0;j<4;++j) b[j] = Bs[kk][tx + 16*j];
      #pragma unroll
      for (int i=0;i<4;++i)
        #pragma unroll
        for (int j=0;j<4;++j) acc[i][j] += a[i]*b[j];
    }
    __syncthreads();
  }
  #pragma unroll
  for (int i=0;i<4;++i) {
    const int r = m0 + ty + 16*i;
    if (r >= M) continue;
    #pragma unroll
    for (int j=0;j<4;++j) {
      const int nn = n0 + tx + 16*j;
      if (nn >= N) continue;
      const int ccol = z*N + nn;
      float v = acc[i][j];
      if (bias) v += bias[ccol];
      if (reluOut) v = fmaxf(v, 0.f);
      stv(&C[(size_t)r*ldc + ccol], v);
    }
  }
}

// ============================================================================
// prep kernels
// ============================================================================
struct Prep17 { const in_t* p[17]; };

__global__ __launch_bounds__(256)
void prep_kernel(Prep17 a, float* __restrict__ pool)
{
  const int len[17] = {1024,1024,128,256,1024,1024,1024,1024,1024,1024,1024,1024,1024,
                       1024,1024,1024,1024};
  const int off[17] = {POOL_BB1,POOL_BB2,POOL_BS1,POOL_BS2,POOL_BS3,POOL_AB1,POOL_AB2,
                       POOL_GB1,POOL_GB2,POOL_SB1,POOL_SB2,POOL_OB1,POOL_OB2,
                       POOL_AB3S,POOL_GB3S,POOL_SB3S,POOL_OB3S};
  const int j = blockIdx.x;
  const in_t* src = a.p[j];
  const int L = len[j], o = off[j];
  for (int i = threadIdx.x; i < L; i += blockDim.x) {
    if (j < 13) {
      pool[o+i] = cvt(src[i]);
    } else {
      float s = 0.f;
      for (int k=0;k<16;++k) s += cvt(src[k*1024 + i]);
      pool[o+i] = s;
    }
  }
}

__global__ __launch_bounds__(64)
void gfeat_kernel(const in_t* __restrict__ f3, float* __restrict__ g)
{
  const int c = blockIdx.x;
  const int t = threadIdx.x;
  float s = (t < 49) ? cvt(f3[c*49 + t]) : 0.f;
  #pragma unroll
  for (int o=32;o>0;o>>=1) s += __shfl_down(s, o, 64);
  if (t == 0) g[c] = s * (1.0f/49.0f);
}

// f32 (R x C) -> bf16 (C x R).  R,C multiples of 64.
__global__ __launch_bounds__(256)
void tcvt_kernel(const float* __restrict__ in, sb_t* __restrict__ outT, int R, int C)
{
  __shared__ float t[64][65];
  const int r0 = blockIdx.x*64, c0 = blockIdx.y*64;
  const int x = threadIdx.x & 63, y = threadIdx.x >> 6;
  #pragma unroll 4
  for (int q=0;q<16;++q){ const int rl = q*4 + y; t[rl][x] = in[(size_t)(r0+rl)*C + c0 + x]; }
  __syncthreads();
  #pragma unroll 4
  for (int q=0;q<16;++q){ const int cl = q*4 + y; stv(&outT[(size_t)(c0+cl)*R + r0 + x], t[x][cl]); }
}

// W (16, Cdim, 64) f32 -> PT (1024, Cdim) bf16 with PT[k*64+u][c] = W[k][c][u]
__global__ __launch_bounds__(256)
void pack_kt_kernel(const float* __restrict__ W, sb_t* __restrict__ PT, int Cdim)
{
  __shared__ float t[64][65];  // [c_local][u]
  const int c0 = blockIdx.x*64; const int k = blockIdx.y;
  const int x = threadIdx.x & 63, y = threadIdx.x >> 6;
  #pragma unroll 4
  for (int q=0;q<16;++q){ const int cl = q*4 + y; t[cl][x] = W[((size_t)k*Cdim + c0 + cl)*64 + x]; }
  __syncthreads();
  #pragma unroll 4
  for (int q=0;q<16;++q){ const int u = q*4 + y; stv(&PT[((size_t)k*64 + u)*Cdim + c0 + x], t[x][u]); }
}

__global__ void cvt_kernel(const float* __restrict__ in, sb_t* __restrict__ o, int n){
  const int i = blockIdx.x*256 + threadIdx.x;
  if (i < n) stv(&o[i], in[i]);
}

// enc fp32 -> bf16 mirror + h fp32/bf16 copies
__global__ __launch_bounds__(256)
void encpost_kernel(const float* __restrict__ oB, sb_t* __restrict__ oBb,
                    float* __restrict__ hB, sb_t* __restrict__ hBb)
{
  const int p = blockIdx.x; const int c = blockIdx.y*256 + threadIdx.x;
  const float v = oB[(size_t)p*1024 + c];
  stv(&oBb[(size_t)p*1024+c], v);
  if (p < NH){ hB[(size_t)p*1024+c] = v; stv(&hBb[(size_t)p*1024+c], v); }
}

// m[p,c] = bf16( relu( (U[p/NB,c] + V[p%NB,c]) * S[p,c] ) )
__global__ __launch_bounds__(256)
void mmake_kernel(const float* __restrict__ U, int hasU, int ldu,
                  const float* __restrict__ V, int hasV,
                  const sb_t* __restrict__ S, sb_t* __restrict__ Mo)
{
  const int p = blockIdx.x;
  const int c = threadIdx.x * 4;
  const size_t base = (size_t)p*1024 + c;
  const ushort4 sv = *(const ushort4*)((const unsigned short*)S + base);
  float a0=0.f,a1=0.f,a2=0.f,a3=0.f;
  if (hasU){ const float* Up = U + (size_t)(p/NB)*ldu + c; a0=Up[0];a1=Up[1];a2=Up[2];a3=Up[3]; }
  if (hasV){ const float* Vp = V + (size_t)(p%NB)*1024 + c; a0+=Vp[0];a1+=Vp[1];a2+=Vp[2];a3+=Vp[3]; }
  ushort4 ov;
  ov.x = f2b(fmaxf(a0*b2f(sv.x),0.f));
  ov.y = f2b(fmaxf(a1*b2f(sv.y),0.f));
  ov.z = f2b(fmaxf(a2*b2f(sv.z),0.f));
  ov.w = f2b(fmaxf(a3*b2f(sv.w),0.f));
  *(ushort4*)((unsigned short*)Mo + base) = ov;
}

// adj[p] = badj + sum_r relu(tmp[p,r] + Ab3s[r]) * Wadj[r]
__global__ __launch_bounds__(256)
void adj_kernel(const float* __restrict__ tmp, const float* __restrict__ ab3s,
                const in_t* __restrict__ Wadj, const in_t* __restrict__ badj,
                float* __restrict__ adj)
{
  __shared__ float red[256];
  const int p = blockIdx.x, t = threadIdx.x;
  float a = 0.f;
  for (int r=t; r<1024; r+=256)
    a += fmaxf(tmp[(size_t)p*1024 + r] + ab3s[r], 0.f) * cvt(Wadj[r]);
  red[t]=a; __syncthreads();
  for (int s=128;s>0;s>>=1){ if(t<s) red[t]+=red[t+s]; __syncthreads(); }
  if (t==0) adj[p] = red[0] + cvt(badj[0]);
}

static __device__ __forceinline__ float bsum(float v, float* red){
  const int t = threadIdx.x;
  red[t]=v; __syncthreads();
  for (int s=512;s>0;s>>=1){ if(t<s) red[t]+=red[t+s]; __syncthreads(); }
  float r = red[0]; __syncthreads();
  return r;
}
static __device__ __forceinline__ float bmax(float v, float* red){
  const int t = threadIdx.x;
  red[t]=v; __syncthreads();
  for (int s=512;s>0;s>>=1){ if(t<s) red[t]=fmaxf(red[t],red[t+s]); __syncthreads(); }
  float r = red[0]; __syncthreads();
  return r;
}

__global__ __launch_bounds__(1024)
void h_update_kernel(const float* __restrict__ adj, const float* __restrict__ mo,
                     const float* __restrict__ ob3s, const in_t* __restrict__ g,
                     const in_t* __restrict__ b, float* __restrict__ h,
                     sb_t* __restrict__ hb)
{
  __shared__ float red[1024];
  __shared__ float w[NB];
  const int hh = blockIdx.x, t = threadIdx.x;
  float av = (t < NB) ? adj[hh*NB + t] : -1e30f;
  float mx = bmax(av, red);
  float e = (t < NB) ? expf(av - mx) : 0.f;
  if (t < NB) w[t] = e;
  float sm = bsum(e, red);
  const float inv = 1.0f / sm;
  float acc = 0.f;
  const float* mop = mo + (size_t)hh*NB*1024 + t;
  for (int n=0; n<NB; ++n) acc += w[n] * mop[(size_t)n*1024];
  acc *= inv;
  float val = h[(size_t)hh*1024 + t] + fmaxf(acc + ob3s[t], 0.f);
  float mean = bsum(val, red) * (1.0f/1024.0f);
  float d = val - mean;
  float var = bsum(d*d, red) * (1.0f/1024.0f);
  float y = d * rsqrtf(var + 1e-5f) * cvt(g[t]) + cvt(b[t]);
  h[(size_t)hh*1024 + t] = y;
  stv(&hb[(size_t)hh*1024 + t], y);
}

__global__ __launch_bounds__(1024)
void o_update_kernel(const float* __restrict__ adj, const float* __restrict__ ms,
                     const float* __restrict__ sb3s, const in_t* __restrict__ g,
                     const in_t* __restrict__ b, float* __restrict__ o,
                     sb_t* __restrict__ ob)
{
  __shared__ float red[1024];
  __shared__ float w[NH];
  const int n = blockIdx.x, t = threadIdx.x;
  float av = (t < NH) ? adj[t*NB + n] : -1e30f;
  float mx = bmax(av, red);
  float e = (t < NH) ? expf(av - mx) : 0.f;
  if (t < NH) w[t] = e;
  float sm = bsum(e, red);
  const float inv = 1.0f / sm;
  float acc = 0.f;
  const float* msp = ms + (size_t)n*1024 + t;
  for (int hh=0; hh<NH; ++hh) acc += w[hh] * msp[(size_t)hh*NB*1024];
  acc *= inv;
  float val = o[(size_t)n*1024 + t] + fmaxf(acc + sb3s[t], 0.f);
  float mean = bsum(val, red) * (1.0f/1024.0f);
  float d = val - mean;
  float var = bsum(d*d, red) * (1.0f/1024.0f);
  float y = d * rsqrtf(var + 1e-5f) * cvt(g[t]) + cvt(b[t]);
  o[(size_t)n*1024 + t] = y;
  stv(&ob[(size_t)n*1024 + t], y);
}

// ---------------- host-side launchers ----------------
template<int RELU, typename TC>
static inline void launch_mfma(hipStream_t st, int M, int N, int K, int ldb,
    const sb_t* A, const sb_t* Bt, const float* bias, TC* C, int ldc, int coff)
{
  dim3 g((unsigned)(M/128), (unsigned)(N/128), 1);
  hipLaunchKernelGGL((gemm_mfma<RELU,TC>), g, dim3(256), 0, st,
                     M,N,K,ldb,A,Bt,bias,C,ldc,coff);
}

template<int MODE, typename TS, typename TC>
static inline void launch_gemm(hipStream_t st, int M, int N, int K,
    const float* U, int ldu, const float* V, int ldv,
    const TS* S, int ldsS, const in_t* B, int ldb, long long strideB, int nz,
    const float* bias, TC* C, int ldc, int relu)
{
  dim3 grid((unsigned)((M+63)/64), (unsigned)((N+63)/64), (unsigned)nz);
  hipLaunchKernelGGL((gemm_kernel<MODE,TS,TC>), grid, dim3(256), 0, st,
                     M,N,K,U,ldu,V,ldv,S,ldsS,B,ldb,strideB,bias,C,ldc,relu);
}

extern "C" void kernel_launch(void* const* d_in, const int* in_sizes, int n_in,
                              void* d_out, int out_size, void* d_ws, size_t ws_size,
                              hipStream_t stream)
{
  (void)in_sizes; (void)n_in; (void)out_size; (void)ws_size;

  const in_t* box  = (const in_t*)d_in[0];
  const in_t* spat = (const in_t*)d_in[1];
  const in_t* f3   = (const in_t*)d_in[2];
  const in_t* Wb1  = (const in_t*)d_in[3];
  const in_t* Wb2  = (const in_t*)d_in[5];
  const in_t* Ws1  = (const in_t*)d_in[7];
  const in_t* Ws2  = (const in_t*)d_in[9];
  const in_t* Ws3  = (const in_t*)d_in[11];
  const in_t* Wadj = (const in_t*)d_in[13];
  const in_t* badj = (const in_t*)d_in[14];
  const in_t* gh   = (const in_t*)d_in[15];
  const in_t* bh   = (const in_t*)d_in[16];
  const in_t* go   = (const in_t*)d_in[17];
  const in_t* bo   = (const in_t*)d_in[18];
  const in_t* A1   = (const in_t*)d_in[19];
  const in_t* A2   = (const in_t*)d_in[21];
  const in_t* A3   = (const in_t*)d_in[23];
  const in_t* G1   = (const in_t*)d_in[25];
  const in_t* G2   = (const in_t*)d_in[27];
  const in_t* G3   = (const in_t*)d_in[29];
  const in_t* S1   = (const in_t*)d_in[31];
  const in_t* S2   = (const in_t*)d_in[33];
  const in_t* S3   = (const in_t*)d_in[35];
  const in_t* O1   = (const in_t*)d_in[37];
  const in_t* O2   = (const in_t*)d_in[39];
  const in_t* O3   = (const in_t*)d_in[41];
  out_t* out = (out_t*)d_out;

  // ---- workspace carve-up (~442 MB) ----
  char* wsb = (char*)d_ws;
  size_t off = 0;
  auto alloc = [&](size_t bytes)->void* {
    void* p = wsb + off; off += (bytes + 255) & ~(size_t)255; return p;
  };
  float* pool  = (float*)alloc((size_t)POOL_TOTAL*4);
  sb_t* Wb1T   = (sb_t*)alloc((size_t)1024*12544*2);
  sb_t* Wb2T   = (sb_t*)alloc((size_t)1024*1024*2);
  sb_t* Ws2T   = (sb_t*)alloc((size_t)256*128*2);
  sb_t* Ws3T   = (sb_t*)alloc((size_t)1024*256*2);
  sb_t* A3T    = (sb_t*)alloc((size_t)1024*1024*2);
  sb_t* O3T    = (sb_t*)alloc((size_t)1024*1024*2);
  sb_t* S3T    = (sb_t*)alloc((size_t)1024*1024*2);
  sb_t* G3T    = (sb_t*)alloc((size_t)1024*1024*2);
  sb_t* A2T    = (sb_t*)alloc((size_t)1024*1024*2);
  sb_t* O2T    = (sb_t*)alloc((size_t)1024*1024*2);
  sb_t* S2T    = (sb_t*)alloc((size_t)1024*1024*2);
  sb_t* G2T    = (sb_t*)alloc((size_t)1024*1024*2);
  sb_t* O1T    = (sb_t*)alloc((size_t)1024*1024*2);
  sb_t* S1T    = (sb_t*)alloc((size_t)1024*1024*2);
  sb_t* A1T    = (sb_t*)alloc((size_t)1024*2048*2);
  sb_t* boxb   = (sb_t*)alloc((size_t)NB*12544*2);
  sb_t* encMidb= (sb_t*)alloc((size_t)NB*EDIM*2);
  float* oB    = (float*)alloc((size_t)NB*EDIM*4);
  sb_t* oBb    = (sb_t*)alloc((size_t)NB*EDIM*2);
  float* hB    = (float*)alloc((size_t)NH*EDIM*4);
  sb_t* hBb    = (sb_t*)alloc((size_t)128*EDIM*2);   // padded to 128 rows
  sb_t* sp1b   = (sb_t*)alloc((size_t)PAIRS*128*2);
  sb_t* sp2b   = (sb_t*)alloc((size_t)PAIRS*256*2);
  sb_t* spFb   = (sb_t*)alloc((size_t)PAIRS*EDIM*2); // aliased as mbuf after s-GEMMs
  sb_t* mbuf   = spFb;
  sb_t* sA     = (sb_t*)alloc((size_t)PAIRS*EDIM*2);
  sb_t* sO     = (sb_t*)alloc((size_t)PAIRS*EDIM*2);
  sb_t* sH     = (sb_t*)alloc((size_t)PAIRS*EDIM*2);
  sb_t* sGb    = (sb_t*)alloc((size_t)PAIRS*EDIM*2);
  float* tmp   = (float*)alloc((size_t)PAIRS*EDIM*4);
  float* ahA   = (float*)alloc((size_t)128*EDIM*4);  // padded
  float* aoA   = (float*)alloc((size_t)NB*EDIM*4);
  float* aoO   = (float*)alloc((size_t)NB*EDIM*4);
  float* ahS   = (float*)alloc((size_t)128*EDIM*4);  // padded
  float* aGv   = (float*)alloc((size_t)EDIM*4);
  float* adj   = (float*)alloc((size_t)PAIRS*4);

  // ---- prep ----
  Prep17 pp;
  const int prepIdx[17] = {4,6,8,10,12,20,22,26,28,32,34,38,40,24,30,36,42};
  for (int i=0;i<17;++i) pp.p[i] = (const in_t*)d_in[prepIdx[i]];
  hipLaunchKernelGGL(prep_kernel, dim3(17), dim3(256), 0, stream, pp, pool);
  hipLaunchKernelGGL(gfeat_kernel, dim3(256), dim3(64), 0, stream, f3, pool + POOL_GFEAT);

  hipLaunchKernelGGL(tcvt_kernel, dim3(196,16), dim3(256), 0, stream, Wb1, Wb1T, 12544, 1024);
  hipLaunchKernelGGL(tcvt_kernel, dim3(16,16),  dim3(256), 0, stream, Wb2, Wb2T, 1024, 1024);
  hipLaunchKernelGGL(tcvt_kernel, dim3(2,4),    dim3(256), 0, stream, Ws2, Ws2T, 128, 256);
  hipLaunchKernelGGL(tcvt_kernel, dim3(4,16),   dim3(256), 0, stream, Ws3, Ws3T, 256, 1024);
  hipLaunchKernelGGL(tcvt_kernel, dim3(16,16),  dim3(256), 0, stream, A3, A3T, 1024, 1024);
  hipLaunchKernelGGL(tcvt_kernel, dim3(16,16),  dim3(256), 0, stream, O3, O3T, 1024, 1024);
  hipLaunchKernelGGL(tcvt_kernel, dim3(16,16),  dim3(256), 0, stream, S3, S3T, 1024, 1024);
  hipLaunchKernelGGL(tcvt_kernel, dim3(16,16),  dim3(256), 0, stream, G3, G3T, 1024, 1024);

  hipLaunchKernelGGL(pack_kt_kernel, dim3(16,16), dim3(256), 0, stream, A2, A2T, 1024);
  hipLaunchKernelGGL(pack_kt_kernel, dim3(16,16), dim3(256), 0, stream, O2, O2T, 1024);
  hipLaunchKernelGGL(pack_kt_kernel, dim3(16,16), dim3(256), 0, stream, S2, S2T, 1024);
  hipLaunchKernelGGL(pack_kt_kernel, dim3(16,16), dim3(256), 0, stream, G2, G2T, 1024);
  hipLaunchKernelGGL(pack_kt_kernel, dim3(16,16), dim3(256), 0, stream, O1, O1T, 1024);
  hipLaunchKernelGGL(pack_kt_kernel, dim3(16,16), dim3(256), 0, stream, S1, S1T, 1024);
  hipLaunchKernelGGL(pack_kt_kernel, dim3(32,16), dim3(256), 0, stream, A1, A1T, 2048);

  hipLaunchKernelGGL(cvt_kernel, dim3((NB*12544)/256), dim3(256), 0, stream,
                     box, boxb, NB*12544);

  // ---- enc = relu(relu(box@Wb1+bb1)@Wb2+bb2); h = enc[:64], o = enc ----
  launch_mfma<1,sb_t >(stream, NB, EDIM, 12544, 12544, boxb, Wb1T, pool+POOL_BB1, encMidb, EDIM, 0);
  launch_mfma<1,float>(stream, NB, EDIM, EDIM,  EDIM,  encMidb, Wb2T, pool+POOL_BB2, oB, EDIM, 0);
  hipLaunchKernelGGL(encpost_kernel, dim3(NB,4), dim3(256), 0, stream, oB, oBb, hB, hBb);

  // ---- spatial MLP: 36 -> 128 -> 256 -> 1024 ----
  launch_gemm<0,float,sb_t>(stream, PAIRS, 128, SPA, nullptr,0,nullptr,0,
      spat, SPA, Ws1, 128, 0, 1, pool+POOL_BS1, sp1b, 128, 1);
  launch_mfma<1,sb_t>(stream, PAIRS, 256,  128, 128, sp1b, Ws2T, pool+POOL_BS2, sp2b, 256, 0);
  launch_mfma<1,sb_t>(stream, PAIRS, EDIM, 256, 256, sp2b, Ws3T, pool+POOL_BS3, spFb, EDIM, 0);

  // ---- loop-invariant s-operands ----
  launch_mfma<0,sb_t>(stream, PAIRS, EDIM, EDIM, EDIM, spFb, A2T, pool+POOL_AB2, sA,  EDIM, 0);
  launch_mfma<0,sb_t>(stream, PAIRS, EDIM, EDIM, EDIM, spFb, O2T, pool+POOL_OB2, sO,  EDIM, 0);
  launch_mfma<0,sb_t>(stream, PAIRS, EDIM, EDIM, EDIM, spFb, S2T, pool+POOL_SB2, sH,  EDIM, 0);
  launch_mfma<0,sb_t>(stream, PAIRS, EDIM, EDIM, EDIM, spFb, G2T, pool+POOL_GB2, sGb, EDIM, 0);

  // ---- aG = gfeat @ G1 + Gb1 (single row, fp32 path) ----
  launch_gemm<0,float,float>(stream, 1, 64, 256, nullptr,0,nullptr,0,
      pool+POOL_GFEAT, 256, G1, 64, 16384, 16, pool+POOL_GB1, aGv, EDIM, 0);

  // ---- 2 message-passing iterations ----
  for (int it=0; it<2; ++it) {
    launch_mfma<0,float>(stream, 128, EDIM, EDIM, 2048, hBb, A1T,      pool+POOL_AB1, ahA, EDIM, 0);
    launch_mfma<0,float>(stream, NB,  EDIM, EDIM, 2048, oBb, A1T+1024, nullptr,       aoA, EDIM, 0);
    hipLaunchKernelGGL(mmake_kernel, dim3(PAIRS), dim3(256), 0, stream,
                       ahA, 1, 1024, aoA, 1, sA, mbuf);
    launch_mfma<0,float>(stream, PAIRS, EDIM, EDIM, EDIM, mbuf, A3T, nullptr, tmp, EDIM, 0);
    hipLaunchKernelGGL(adj_kernel, dim3(PAIRS), dim3(256), 0, stream,
                       tmp, pool+POOL_AB3S, Wadj, badj, adj);

    launch_mfma<0,float>(stream, NB, EDIM, EDIM, EDIM, oBb, O1T, pool+POOL_OB1, aoO, EDIM, 0);
    hipLaunchKernelGGL(mmake_kernel, dim3(PAIRS), dim3(256), 0, stream,
                       nullptr, 0, 0, aoO, 1, sO, mbuf);
    launch_mfma<0,float>(stream, PAIRS, EDIM, EDIM, EDIM, mbuf, O3T, nullptr, tmp, EDIM, 0);
    hipLaunchKernelGGL(h_update_kernel, dim3(NH), dim3(1024), 0, stream,
                       adj, tmp, pool+POOL_OB3S, gh, bh, hB, hBb);

    launch_mfma<0,float>(stream, 128, EDIM, EDIM, EDIM, hBb, S1T, pool+POOL_SB1, ahS, EDIM, 0);
    hipLaunchKernelGGL(mmake_kernel, dim3(PAIRS), dim3(256), 0, stream,
                       ahS, 1, 1024, nullptr, 0, sH, mbuf);
    launch_mfma<0,float>(stream, PAIRS, EDIM, EDIM, EDIM, mbuf, S3T, nullptr, tmp, EDIM, 0);
    hipLaunchKernelGGL(o_update_kernel, dim3(NB), dim3(1024), 0, stream,
                       adj, tmp, pool+POOL_SB3S, go, bo, oB, oBb);
  }

  // ---- final heads ----
  launch_mfma<0,float>(stream, 128, EDIM, EDIM, 2048, hBb, A1T,      pool+POOL_AB1, ahA, EDIM, 0);
  launch_mfma<0,float>(stream, NB,  EDIM, EDIM, 2048, oBb, A1T+1024, nullptr,       aoA, EDIM, 0);
  hipLaunchKernelGGL(mmake_kernel, dim3(PAIRS), dim3(256), 0, stream,
                     ahA, 1, 1024, aoA, 1, sA, mbuf);
  launch_mfma<1,out_t>(stream, PAIRS, EDIM, EDIM, EDIM, mbuf, A3T, pool+POOL_AB3S, out, 2048, 0);

  hipLaunchKernelGGL(mmake_kernel, dim3(PAIRS), dim3(256), 0, stream,
                     aGv, 1, 0, nullptr, 0, sGb, mbuf);
  launch_mfma<1,out_t>(stream, PAIRS, EDIM, EDIM, EDIM, mbuf, G3T, pool+POOL_GB3S, out, 2048, 1024);
}

// Round 3
// 1716.772 us; speedup vs baseline: 11.2375x; 1.4213x over previous
//
#include <hip/hip_runtime.h>
#include <hip/hip_bf16.h>
#include <cstdint>
#include <cstddef>

// ---------------- problem constants ----------------
#define NH    64
#define NB    384
#define EDIM  1024
#define PAIRS (NH*NB)   // 24576
#define SPA   36

using in_t  = float;
using out_t = float;
using sb_t  = __hip_bfloat16;

typedef short bf16x8 __attribute__((ext_vector_type(8)));
typedef float f32x4  __attribute__((ext_vector_type(4)));

static __device__ __forceinline__ float cvt(float x){ return x; }
static __device__ __forceinline__ float cvt(__hip_bfloat16 x){ return __bfloat162float(x); }
static __device__ __forceinline__ void stv(float* p, float v){ *p = v; }
static __device__ __forceinline__ void stv(__hip_bfloat16* p, float v){ *p = __float2bfloat16(v); }

static __device__ __forceinline__ float b2f(unsigned short u){
  union { unsigned int i; float f; } x; x.i = ((unsigned int)u)<<16; return x.f;
}

typedef const __attribute__((address_space(1))) void* as1_t;
typedef __attribute__((address_space(3))) void* as3_t;
static __device__ __forceinline__ void gl_lds16(const void* g, void* l){
  __builtin_amdgcn_global_load_lds((as1_t)g, (as3_t)l, 16, 0, 0);
}

// ---------------- bias/constant pool layout (floats) ----------------
#define POOL_BB1   0
#define POOL_BB2   1024
#define POOL_BS1   2048
#define POOL_BS2   2176
#define POOL_BS3   2432
#define POOL_AB1   3456
#define POOL_GB1   4480
#define POOL_SB1   5504
#define POOL_OB1   6528
#define POOL_B2ALL 7552          // 4096: [AB2|OB2|SB2|GB2]
#define POOL_AB3S  11648
#define POOL_GB3S  12672
#define POOL_SB3S  13696
#define POOL_OB3S  14720
#define POOL_GFEAT 15744
#define POOL_TOTAL 16000

// ============================================================================
// MFMA bf16 GEMM, 128x128 tile, BK=64 (two 32-wide sub-tiles), 4 waves.
// C = A[MxK] @ Bt[NxK]^T ; M%128==0, N%128==0, KS%64==0.
// EPI 0: C[row, coff+col] = (relu?)(acc + bias[col+coff_bias-free])   (bias indexed by col)
// EPI 1: adjOut[row] atomicAdd  sum_col relu(acc+ab3s[col])*Wadj[col]
// EPI 2: C[z*strideCz + row*ldc + col] = acc   (split-K partial)
// blockIdx.z selects K-chunk [z*KS, (z+1)*KS)
// ============================================================================
template<int EPI, int RELU, typename TC>
__global__ __launch_bounds__(256)
void gemm_mfma(int M, int N, int KS, int lda, int ldb,
               const sb_t* __restrict__ A,
               const sb_t* __restrict__ Bt,
               const float* __restrict__ bias,
               TC* __restrict__ C, int ldc, int coff, long long strideCz,
               const float* __restrict__ Wadj,
               const float* __restrict__ ab3s,
               float* __restrict__ adjOut)
{
  __shared__ alignas(16) short lA[2][128*32];
  __shared__ alignas(16) short lB[2][128*32];
  const int tid = threadIdx.x;
  const int w = tid >> 6, l = tid & 63;
  const int m0 = blockIdx.x * 128, n0 = blockIdx.y * 128;
  const int wr = w >> 1, wc = w & 1;
  const int Koff = blockIdx.z * KS;

  const int srow = w*32 + (l>>2);
  const int scol = (l&3)*8;
  const sb_t* gA = A  + (size_t)(m0 + srow)*(size_t)lda + Koff + scol;
  const sb_t* gB = Bt + (size_t)(n0 + srow)*(size_t)ldb + Koff + scol;
  short* lA0 = &lA[0][(w*32)*32];
  short* lA1 = &lA[1][(w*32)*32];
  short* lB0 = &lB[0][(w*32)*32];
  short* lB1 = &lB[1][(w*32)*32];

  f32x4 acc[4][4];
  const f32x4 zz = {0.f,0.f,0.f,0.f};
  #pragma unroll
  for (int i=0;i<4;++i)
    #pragma unroll
    for (int j=0;j<4;++j) acc[i][j] = zz;

  const int fr  = l & 15;
  const int fko = (l >> 4) * 8;

  for (int k0 = 0; k0 < KS; k0 += 64) {
    gl_lds16(gA + k0,               lA0);
    gl_lds16(gA + k0 + 16*lda,      lA0 + 16*32);
    gl_lds16(gA + k0 + 32,          lA1);
    gl_lds16(gA + k0 + 32 + 16*lda, lA1 + 16*32);
    gl_lds16(gB + k0,               lB0);
    gl_lds16(gB + k0 + 16*ldb,      lB0 + 16*32);
    gl_lds16(gB + k0 + 32,          lB1);
    gl_lds16(gB + k0 + 32 + 16*ldb, lB1 + 16*32);
    __syncthreads();
    #pragma unroll
    for (int kh=0; kh<2; ++kh) {
      bf16x8 af[4], bfv[4];
      #pragma unroll
      for (int i=0;i<4;++i)
        af[i]  = *(const bf16x8*)&lA[kh][(wr*64 + i*16 + fr)*32 + fko];
      #pragma unroll
      for (int j=0;j<4;++j)
        bfv[j] = *(const bf16x8*)&lB[kh][(wc*64 + j*16 + fr)*32 + fko];
      #pragma unroll
      for (int i=0;i<4;++i)
        #pragma unroll
        for (int j=0;j<4;++j)
          acc[i][j] = __builtin_amdgcn_mfma_f32_16x16x32_bf16(af[i], bfv[j], acc[i][j], 0, 0, 0);
    }
    __syncthreads();
  }

  const int cn = l & 15;
  const int cr = (l >> 4) * 4;

  if (EPI == 1) {
    float part[4][4];
    #pragma unroll
    for (int i=0;i<4;++i)
      #pragma unroll
      for (int r=0;r<4;++r) part[i][r] = 0.f;
    #pragma unroll
    for (int j=0;j<4;++j) {
      const int col = n0 + wc*64 + j*16 + cn;
      const float wv = Wadj[col];
      const float bv = ab3s[col];
      #pragma unroll
      for (int i=0;i<4;++i)
        #pragma unroll
        for (int r=0;r<4;++r)
          part[i][r] += fmaxf(acc[i][j][r] + bv, 0.f) * wv;
    }
    #pragma unroll
    for (int m=1;m<16;m<<=1)
      #pragma unroll
      for (int i=0;i<4;++i)
        #pragma unroll
        for (int r=0;r<4;++r)
          part[i][r] += __shfl_xor(part[i][r], m, 64);
    if (cn == 0) {
      #pragma unroll
      for (int i=0;i<4;++i)
        #pragma unroll
        for (int r=0;r<4;++r)
          atomicAdd(&adjOut[m0 + wr*64 + i*16 + cr + r], part[i][r]);
    }
    return;
  }

  #pragma unroll
  for (int j=0;j<4;++j) {
    const int col = n0 + wc*64 + j*16 + cn;
    const float bv = (EPI==0 && bias) ? bias[col] : 0.f;
    #pragma unroll
    for (int i=0;i<4;++i) {
      #pragma unroll
      for (int r=0;r<4;++r) {
        const int row = m0 + wr*64 + i*16 + cr + r;
        float v = acc[i][j][r] + bv;
        if (RELU) v = fmaxf(v, 0.f);
        if (EPI == 2)
          stv(&C[(size_t)blockIdx.z*strideCz + (size_t)row*ldc + col], v);
        else
          stv(&C[(size_t)row*ldc + coff + col], v);
      }
    }
  }
}

// ============================================================================
// fp32 VALU GEMM (tiny/odd shapes: spatial 36->128, gfeat@G1)
// ============================================================================
template<typename TC>
__global__ __launch_bounds__(256)
void gemm_valu(int M, int N, int K,
               const in_t* __restrict__ S, int ldsS,
               const in_t* __restrict__ B, int ldb, long long strideB,
               const float* __restrict__ bias,
               TC* __restrict__ C, int ldc, int reluOut)
{
  __shared__ float As[16][65];
  __shared__ float Bs[16][68];
  const int z  = blockIdx.z;
  const in_t* Bz = B + (long long)z * strideB;
  const int m0 = blockIdx.x * 64;
  const int n0 = blockIdx.y * 64;
  const int tid = threadIdx.x;
  const int tx = tid & 15;
  const int ty = tid >> 4;

  float acc[4][4];
  #pragma unroll
  for (int i=0;i<4;++i)
    #pragma unroll
    for (int j=0;j<4;++j) acc[i][j]=0.f;

  const int kTiles = (K + 15) >> 4;
  for (int kt=0; kt<kTiles; ++kt) {
    const int k0 = kt << 4;
    #pragma unroll
    for (int q=0;q<4;++q) {
      const int p = m0 + ty + 16*q;
      const int c = k0 + tx;
      As[tx][ty+16*q] = (p < M && c < K) ? S[(size_t)p*ldsS + c] : 0.f;
    }
    {
      const int n = tid & 63;
      #pragma unroll
      for (int q=0;q<4;++q) {
        const int kk = (tid >> 6) + 4*q;
        const int gk = k0 + kk;
        const int gn = n0 + n;
        Bs[kk][n] = (gk < K && gn < N) ? Bz[(size_t)gk*ldb + gn] : 0.f;
      }
    }
    __syncthreads();
    #pragma unroll
    for (int kk=0; kk<16; ++kk) {
      float a[4], b[4];
      #pragma unroll
      for (int i=0;i<4;++i) a[i] = As[kk][ty + 16*i];
      #pragma unroll
      for (int j=0;j<4;++j) b[j] = Bs[kk][tx + 16*j];
      #pragma unroll
      for (int i=0;i<4;++i)
        #pragma unroll
        for (int j=0;j<4;++j) acc[i][j] += a[i]*b[j];
    }
    __syncthreads();
  }
  #pragma unroll
  for (int i=0;i<4;++i) {
    const int r = m0 + ty + 16*i;
    if (r >= M) continue;
    #pragma unroll
    for (int j=0;j<4;++j) {
      const int nn = n0 + tx + 16*j;
      if (nn >= N) continue;
      const int ccol = z*N + nn;
      float v = acc[i][j];
      if (bias) v += bias[ccol];
      if (reluOut) v = fmaxf(v, 0.f);
      stv(&C[(size_t)r*ldc + ccol], v);
    }
  }
}

// ============================================================================
// prep kernels
// ============================================================================
struct Prep17 { const in_t* p[17]; };

__global__ __launch_bounds__(256)
void prep_kernel(Prep17 a, float* __restrict__ pool)
{
  const int len[17] = {1024,1024,128,256,1024,1024,1024,1024,1024,1024,1024,1024,1024,
                       1024,1024,1024,1024};
  const int off[17] = {POOL_BB1,POOL_BB2,POOL_BS1,POOL_BS2,POOL_BS3,POOL_AB1,
                       POOL_B2ALL+0,      // AB2
                       POOL_GB1,
                       POOL_B2ALL+3072,   // GB2
                       POOL_SB1,
                       POOL_B2ALL+2048,   // SB2
                       POOL_OB1,
                       POOL_B2ALL+1024,   // OB2
                       POOL_AB3S,POOL_GB3S,POOL_SB3S,POOL_OB3S};
  const int j = blockIdx.x;
  const in_t* src = a.p[j];
  const int L = len[j], o = off[j];
  for (int i = threadIdx.x; i < L; i += blockDim.x) {
    if (j < 13) {
      pool[o+i] = src[i];
    } else {
      float s = 0.f;
      for (int k=0;k<16;++k) s += src[k*1024 + i];
      pool[o+i] = s;
    }
  }
}

__global__ __launch_bounds__(64)
void gfeat_kernel(const in_t* __restrict__ f3, float* __restrict__ g)
{
  const int c = blockIdx.x;
  const int t = threadIdx.x;
  float s = (t < 49) ? f3[c*49 + t] : 0.f;
  #pragma unroll
  for (int o=32;o>0;o>>=1) s += __shfl_down(s, o, 64);
  if (t == 0) g[c] = s * (1.0f/49.0f);
}

// f32 (R x C) -> bf16 (C x R)
__global__ __launch_bounds__(256)
void tcvt_kernel(const float* __restrict__ in, sb_t* __restrict__ outT, int R, int C)
{
  __shared__ float t[64][65];
  const int r0 = blockIdx.x*64, c0 = blockIdx.y*64;
  const int x = threadIdx.x & 63, y = threadIdx.x >> 6;
  #pragma unroll 4
  for (int q=0;q<16;++q){ const int rl = q*4 + y; t[rl][x] = in[(size_t)(r0+rl)*C + c0 + x]; }
  __syncthreads();
  #pragma unroll 4
  for (int q=0;q<16;++q){ const int cl = q*4 + y; stv(&outT[(size_t)(c0+cl)*R + r0 + x], t[x][cl]); }
}

// W (16, Cdim, 64) f32 -> PT[k*64+u][c] bf16
__global__ __launch_bounds__(256)
void pack_kt_kernel(const float* __restrict__ W, sb_t* __restrict__ PT, int Cdim)
{
  __shared__ float t[64][65];
  const int c0 = blockIdx.x*64; const int k = blockIdx.y;
  const int x = threadIdx.x & 63, y = threadIdx.x >> 6;
  #pragma unroll 4
  for (int q=0;q<16;++q){ const int cl = q*4 + y; t[cl][x] = W[((size_t)k*Cdim + c0 + cl)*64 + x]; }
  __syncthreads();
  #pragma unroll 4
  for (int q=0;q<16;++q){ const int u = q*4 + y; stv(&PT[((size_t)k*64 + u)*Cdim + c0 + x], t[x][u]); }
}

__global__ void cvt_kernel(const float* __restrict__ in, sb_t* __restrict__ o, int n){
  const int i = blockIdx.x*256 + threadIdx.x;
  if (i < n) stv(&o[i], in[i]);
}

// combine 4 split-K partials + bias + relu -> bf16
__global__ __launch_bounds__(256)
void combine4_kernel(const float* __restrict__ part, const float* __restrict__ bias,
                     sb_t* __restrict__ o)
{
  const int i = blockIdx.x*256 + threadIdx.x;   // over 384*1024
  const int c = i & 1023;
  float v = part[i] + part[i+393216] + part[i+2*393216] + part[i+3*393216] + bias[c];
  stv(&o[i], fmaxf(v, 0.f));
}

// enc fp32 -> bf16 mirror + h fp32/bf16 copies
__global__ __launch_bounds__(256)
void encpost_kernel(const float* __restrict__ oB, sb_t* __restrict__ oBb,
                    float* __restrict__ hB, sb_t* __restrict__ hBb)
{
  const int p = blockIdx.x; const int c = blockIdx.y*256 + threadIdx.x;
  const float v = oB[(size_t)p*1024 + c];
  stv(&oBb[(size_t)p*1024+c], v);
  if (p < NH){ hB[(size_t)p*1024+c] = v; stv(&hBb[(size_t)p*1024+c], v); }
}

// m[p,c] = bf16( relu( (U[p/NB,c] + V[p%NB,c]) * S4[p, colOff+c] ) )
__global__ __launch_bounds__(256)
void mmake_kernel(const float* __restrict__ U, int hasU, int ldu,
                  const float* __restrict__ V, int hasV,
                  const sb_t* __restrict__ S, int ldS, int colOff,
                  sb_t* __restrict__ Mo)
{
  const int p = blockIdx.x;
  const int c = threadIdx.x * 4;
  const ushort4 sv = *(const ushort4*)((const unsigned short*)S + (size_t)p*ldS + colOff + c);
  float a0=0.f,a1=0.f,a2=0.f,a3=0.f;
  if (hasU){ const float* Up = U + (size_t)(p/NB)*ldu + c; a0=Up[0];a1=Up[1];a2=Up[2];a3=Up[3]; }
  if (hasV){ const float* Vp = V + (size_t)(p%NB)*1024 + c; a0+=Vp[0];a1+=Vp[1];a2+=Vp[2];a3+=Vp[3]; }
  __hip_bfloat16* mo = (__hip_bfloat16*)Mo + (size_t)p*1024 + c;
  mo[0] = __float2bfloat16(fmaxf(a0*b2f(sv.x),0.f));
  mo[1] = __float2bfloat16(fmaxf(a1*b2f(sv.y),0.f));
  mo[2] = __float2bfloat16(fmaxf(a2*b2f(sv.z),0.f));
  mo[3] = __float2bfloat16(fmaxf(a3*b2f(sv.w),0.f));
}

// softmax over n of adj[hh,:] -> wh[hh,n]
__global__ __launch_bounds__(512)
void smax_h_kernel(const float* __restrict__ adj, float* __restrict__ wh)
{
  __shared__ float red[512];
  const int hh = blockIdx.x, t = threadIdx.x;
  float av = (t < NB) ? adj[hh*NB + t] : -1e30f;
  red[t]=av; __syncthreads();
  for (int s=256;s>0;s>>=1){ if(t<s) red[t]=fmaxf(red[t],red[t+s]); __syncthreads(); }
  float mx = red[0]; __syncthreads();
  float e = (t < NB) ? __expf(av - mx) : 0.f;
  red[t]=e; __syncthreads();
  for (int s=256;s>0;s>>=1){ if(t<s) red[t]+=red[t+s]; __syncthreads(); }
  if (t < NB) wh[hh*NB + t] = e / red[0];
}

// softmax over h of adj[:,n] -> wo[n,h]
__global__ __launch_bounds__(64)
void smax_o_kernel(const float* __restrict__ adj, float* __restrict__ wo)
{
  const int n = blockIdx.x, t = threadIdx.x;
  float av = adj[t*NB + n];
  float mx = av;
  #pragma unroll
  for (int o=32;o>0;o>>=1) mx = fmaxf(mx, __shfl_xor(mx, o, 64));
  float e = __expf(av - mx);
  float s = e;
  #pragma unroll
  for (int o=32;o>0;o>>=1) s += __shfl_xor(s, o, 64);
  wo[n*64 + t] = e / s;
}

// mw_h[hh,c] = sum_n wh[hh,n]*relu(aoO[n,c]*sO[hh*NB+n, c])   (sO = s4 col-slice)
__global__ __launch_bounds__(128)
void wredH_kernel(const float* __restrict__ wh, const float* __restrict__ ao,
                  const sb_t* __restrict__ s4, int colOff, sb_t* __restrict__ mw)
{
  const int hh = blockIdx.x;
  const int c = blockIdx.y*128 + threadIdx.x;
  const unsigned short* sp = (const unsigned short*)s4 + (size_t)hh*NB*4096 + colOff + c;
  const float* whp = wh + hh*NB;
  float acc = 0.f;
  for (int n=0; n<NB; ++n)
    acc += whp[n] * fmaxf(ao[(size_t)n*1024 + c] * b2f(sp[(size_t)n*4096]), 0.f);
  stv(&mw[(size_t)hh*1024 + c], acc);
}

// mw_o[n,c] = sum_h wo[n,h]*relu(ahS[h,c]*sH[h*NB+n, c])
__global__ __launch_bounds__(128)
void wredO_kernel(const float* __restrict__ wo, const float* __restrict__ ah,
                  const sb_t* __restrict__ s4, int colOff, sb_t* __restrict__ mw)
{
  const int n = blockIdx.x;
  const int c = blockIdx.y*128 + threadIdx.x;
  const unsigned short* sp = (const unsigned short*)s4 + (size_t)n*4096 + colOff + c;
  const float* wop = wo + n*64;
  float acc = 0.f;
  for (int h=0; h<NH; ++h)
    acc += wop[h] * fmaxf(ah[(size_t)h*1024 + c] * b2f(sp[(size_t)h*NB*4096]), 0.f);
  stv(&mw[(size_t)n*1024 + c], acc);
}

static __device__ __forceinline__ float bsum(float v, float* red){
  const int t = threadIdx.x;
  red[t]=v; __syncthreads();
  for (int s=512;s>0;s>>=1){ if(t<s) red[t]+=red[t+s]; __syncthreads(); }
  float r = red[0]; __syncthreads();
  return r;
}

// x[row,:] = LN( x + relu(msg[row,:] + b3s) ) * g + b ; also bf16 mirror
__global__ __launch_bounds__(1024)
void ln_update_kernel(const float* __restrict__ msg, const float* __restrict__ b3s,
                      const in_t* __restrict__ g, const in_t* __restrict__ b,
                      float* __restrict__ x, sb_t* __restrict__ xb)
{
  __shared__ float red[1024];
  const int row = blockIdx.x, t = threadIdx.x;
  float val = x[(size_t)row*1024 + t] + fmaxf(msg[(size_t)row*1024 + t] + b3s[t], 0.f);
  float mean = bsum(val, red) * (1.0f/1024.0f);
  float d = val - mean;
  float var = bsum(d*d, red) * (1.0f/1024.0f);
  float y = d * rsqrtf(var + 1e-5f) * g[t] + b[t];
  x[(size_t)row*1024 + t] = y;
  stv(&xb[(size_t)row*1024 + t], y);
}

// ---------------- host-side launchers ----------------
template<int EPI, int RELU, typename TC>
static inline void launch_mfma(hipStream_t st, int M, int N, int KS, int lda, int ldb, int nz,
    const sb_t* A, const sb_t* Bt, const float* bias, TC* C, int ldc, int coff,
    long long strideCz, const float* Wadj, const float* ab3s, float* adjOut)
{
  dim3 g((unsigned)(M/128), (unsigned)(N/128), (unsigned)nz);
  hipLaunchKernelGGL((gemm_mfma<EPI,RELU,TC>), g, dim3(256), 0, st,
                     M,N,KS,lda,ldb,A,Bt,bias,C,ldc,coff,strideCz,Wadj,ab3s,adjOut);
}

extern "C" void kernel_launch(void* const* d_in, const int* in_sizes, int n_in,
                              void* d_out, int out_size, void* d_ws, size_t ws_size,
                              hipStream_t stream)
{
  (void)in_sizes; (void)n_in; (void)out_size; (void)ws_size;

  const in_t* box  = (const in_t*)d_in[0];
  const in_t* spat = (const in_t*)d_in[1];
  const in_t* f3   = (const in_t*)d_in[2];
  const in_t* Wb1  = (const in_t*)d_in[3];
  const in_t* Wb2  = (const in_t*)d_in[5];
  const in_t* Ws1  = (const in_t*)d_in[7];
  const in_t* Ws2  = (const in_t*)d_in[9];
  const in_t* Ws3  = (const in_t*)d_in[11];
  const in_t* Wadj = (const in_t*)d_in[13];
  const in_t* gh   = (const in_t*)d_in[15];
  const in_t* bh   = (const in_t*)d_in[16];
  const in_t* go   = (const in_t*)d_in[17];
  const in_t* bo   = (const in_t*)d_in[18];
  const in_t* A1   = (const in_t*)d_in[19];
  const in_t* A2   = (const in_t*)d_in[21];
  const in_t* A3   = (const in_t*)d_in[23];
  const in_t* G1   = (const in_t*)d_in[25];
  const in_t* G2   = (const in_t*)d_in[27];
  const in_t* G3   = (const in_t*)d_in[29];
  const in_t* S1   = (const in_t*)d_in[31];
  const in_t* S2   = (const in_t*)d_in[33];
  const in_t* S3   = (const in_t*)d_in[35];
  const in_t* O1   = (const in_t*)d_in[37];
  const in_t* O2   = (const in_t*)d_in[39];
  const in_t* O3   = (const in_t*)d_in[41];
  out_t* out = (out_t*)d_out;

  // ---- workspace ----
  char* wsb = (char*)d_ws;
  size_t off = 0;
  auto alloc = [&](size_t bytes)->void* {
    void* p = wsb + off; off += (bytes + 255) & ~(size_t)255; return p;
  };
  float* pool   = (float*)alloc((size_t)POOL_TOTAL*4);
  sb_t* Wb1T    = (sb_t*)alloc((size_t)1024*12544*2);
  sb_t* Wb2T    = (sb_t*)alloc((size_t)1024*1024*2);
  sb_t* Ws2T    = (sb_t*)alloc((size_t)256*128*2);
  sb_t* Ws3T    = (sb_t*)alloc((size_t)1024*256*2);
  sb_t* A3T     = (sb_t*)alloc((size_t)1024*1024*2);
  sb_t* O3T     = (sb_t*)alloc((size_t)1024*1024*2);
  sb_t* S3T     = (sb_t*)alloc((size_t)1024*1024*2);
  sb_t* G3T     = (sb_t*)alloc((size_t)1024*1024*2);
  sb_t* s2Tall  = (sb_t*)alloc((size_t)4096*1024*2);  // [A2|O2|S2|G2] rows
  sb_t* O1T     = (sb_t*)alloc((size_t)1024*1024*2);
  sb_t* S1T     = (sb_t*)alloc((size_t)1024*1024*2);
  sb_t* A1T     = (sb_t*)alloc((size_t)1024*2048*2);
  sb_t* boxb    = (sb_t*)alloc((size_t)NB*12544*2);
  float* encP   = (float*)alloc((size_t)4*NB*EDIM*4);  // split-K partials
  sb_t* encMidb = (sb_t*)alloc((size_t)NB*EDIM*2);
  float* oB     = (float*)alloc((size_t)NB*EDIM*4);
  sb_t* oBb     = (sb_t*)alloc((size_t)NB*EDIM*2);
  float* hB     = (float*)alloc((size_t)NH*EDIM*4);
  sb_t* hBb     = (sb_t*)alloc((size_t)128*EDIM*2);
  sb_t* sp1b    = (sb_t*)alloc((size_t)PAIRS*128*2);
  sb_t* sp2b    = (sb_t*)alloc((size_t)PAIRS*256*2);
  sb_t* spFb    = (sb_t*)alloc((size_t)PAIRS*EDIM*2); // aliased as mbuf later
  sb_t* mbuf    = spFb;
  sb_t* s4      = (sb_t*)alloc((size_t)PAIRS*4096*2); // [sA|sO|sS|sG]
  float* ahA    = (float*)alloc((size_t)128*EDIM*4);
  float* aoA    = (float*)alloc((size_t)NB*EDIM*4);
  float* aoO    = (float*)alloc((size_t)NB*EDIM*4);
  float* ahS    = (float*)alloc((size_t)128*EDIM*4);
  float* aGv    = (float*)alloc((size_t)EDIM*4);
  float* adj    = (float*)alloc((size_t)PAIRS*4);
  float* wh     = (float*)alloc((size_t)PAIRS*4);
  float* wo     = (float*)alloc((size_t)PAIRS*4);
  sb_t* mwH     = (sb_t*)alloc((size_t)128*EDIM*2);
  sb_t* mwO     = (sb_t*)alloc((size_t)NB*EDIM*2);
  float* hmsg   = (float*)alloc((size_t)128*EDIM*4);
  float* omsg   = (float*)alloc((size_t)NB*EDIM*4);

  // ---- prep ----
  Prep17 pp;
  const int prepIdx[17] = {4,6,8,10,12,20,22,26,28,32,34,38,40,24,30,36,42};
  for (int i=0;i<17;++i) pp.p[i] = (const in_t*)d_in[prepIdx[i]];
  hipLaunchKernelGGL(prep_kernel, dim3(17), dim3(256), 0, stream, pp, pool);
  hipLaunchKernelGGL(gfeat_kernel, dim3(256), dim3(64), 0, stream, f3, pool + POOL_GFEAT);

  hipLaunchKernelGGL(tcvt_kernel, dim3(196,16), dim3(256), 0, stream, Wb1, Wb1T, 12544, 1024);
  hipLaunchKernelGGL(tcvt_kernel, dim3(16,16),  dim3(256), 0, stream, Wb2, Wb2T, 1024, 1024);
  hipLaunchKernelGGL(tcvt_kernel, dim3(2,4),    dim3(256), 0, stream, Ws2, Ws2T, 128, 256);
  hipLaunchKernelGGL(tcvt_kernel, dim3(4,16),   dim3(256), 0, stream, Ws3, Ws3T, 256, 1024);
  hipLaunchKernelGGL(tcvt_kernel, dim3(16,16),  dim3(256), 0, stream, A3, A3T, 1024, 1024);
  hipLaunchKernelGGL(tcvt_kernel, dim3(16,16),  dim3(256), 0, stream, O3, O3T, 1024, 1024);
  hipLaunchKernelGGL(tcvt_kernel, dim3(16,16),  dim3(256), 0, stream, S3, S3T, 1024, 1024);
  hipLaunchKernelGGL(tcvt_kernel, dim3(16,16),  dim3(256), 0, stream, G3, G3T, 1024, 1024);

  hipLaunchKernelGGL(pack_kt_kernel, dim3(16,16), dim3(256), 0, stream, A2, s2Tall,            1024);
  hipLaunchKernelGGL(pack_kt_kernel, dim3(16,16), dim3(256), 0, stream, O2, s2Tall+1024*1024,  1024);
  hipLaunchKernelGGL(pack_kt_kernel, dim3(16,16), dim3(256), 0, stream, S2, s2Tall+2048*1024,  1024);
  hipLaunchKernelGGL(pack_kt_kernel, dim3(16,16), dim3(256), 0, stream, G2, s2Tall+3072*1024,  1024);
  hipLaunchKernelGGL(pack_kt_kernel, dim3(16,16), dim3(256), 0, stream, O1, O1T, 1024);
  hipLaunchKernelGGL(pack_kt_kernel, dim3(16,16), dim3(256), 0, stream, S1, S1T, 1024);
  hipLaunchKernelGGL(pack_kt_kernel, dim3(32,16), dim3(256), 0, stream, A1, A1T, 2048);

  hipLaunchKernelGGL(cvt_kernel, dim3((NB*12544)/256), dim3(256), 0, stream, box, boxb, NB*12544);

  // ---- enc: split-K box GEMM (KS=3136, z=4) + combine, then @Wb2 ----
  launch_mfma<2,0,float>(stream, NB, EDIM, 3136, 12544, 12544, 4,
      boxb, Wb1T, nullptr, encP, EDIM, 0, (long long)NB*EDIM, nullptr, nullptr, nullptr);
  hipLaunchKernelGGL(combine4_kernel, dim3(NB*EDIM/256), dim3(256), 0, stream,
                     encP, pool+POOL_BB1, encMidb);
  launch_mfma<0,1,float>(stream, NB, EDIM, EDIM, EDIM, EDIM, 1,
      encMidb, Wb2T, pool+POOL_BB2, oB, EDIM, 0, 0, nullptr, nullptr, nullptr);
  hipLaunchKernelGGL(encpost_kernel, dim3(NB,4), dim3(256), 0, stream, oB, oBb, hB, hBb);

  // ---- spatial MLP ----
  {
    dim3 g((PAIRS+63)/64, 2, 1);
    hipLaunchKernelGGL((gemm_valu<sb_t>), g, dim3(256), 0, stream,
        PAIRS, 128, SPA, spat, SPA, Ws1, 128, 0, pool+POOL_BS1, sp1b, 128, 1);
  }
  launch_mfma<0,1,sb_t>(stream, PAIRS, 256, 128, 128, 128, 1,
      sp1b, Ws2T, pool+POOL_BS2, sp2b, 256, 0, 0, nullptr, nullptr, nullptr);
  launch_mfma<0,1,sb_t>(stream, PAIRS, EDIM, 256, 256, 256, 1,
      sp2b, Ws3T, pool+POOL_BS3, spFb, EDIM, 0, 0, nullptr, nullptr, nullptr);

  // ---- fused s-precompute: s4 = spF @ [A2|O2|S2|G2] + b2  (N=4096) ----
  launch_mfma<0,0,sb_t>(stream, PAIRS, 4096, EDIM, EDIM, EDIM, 1,
      spFb, s2Tall, pool+POOL_B2ALL, s4, 4096, 0, 0, nullptr, nullptr, nullptr);

  // ---- aG = gfeat @ G1 + Gb1 (single row) ----
  {
    dim3 g(1, 1, 16);
    hipLaunchKernelGGL((gemm_valu<float>), g, dim3(256), 0, stream,
        1, 64, 256, pool+POOL_GFEAT, 256, G1, 64, 16384, pool+POOL_GB1, aGv, EDIM, 0);
  }

  // ---- 2 message-passing iterations ----
  for (int it=0; it<2; ++it) {
    // A-path -> adj
    launch_mfma<0,0,float>(stream, 128, EDIM, EDIM, EDIM, 2048, 1,
        hBb, A1T, pool+POOL_AB1, ahA, EDIM, 0, 0, nullptr, nullptr, nullptr);
    launch_mfma<0,0,float>(stream, NB, EDIM, EDIM, EDIM, 2048, 1,
        oBb, A1T+1024, nullptr, aoA, EDIM, 0, 0, nullptr, nullptr, nullptr);
    hipLaunchKernelGGL(mmake_kernel, dim3(PAIRS), dim3(256), 0, stream,
                       ahA, 1, 1024, aoA, 1, s4, 4096, 0, mbuf);
    hipMemsetAsync(adj, 0, (size_t)PAIRS*4, stream);
    launch_mfma<1,0,float>(stream, PAIRS, EDIM, EDIM, EDIM, EDIM, 1,
        mbuf, A3T, nullptr, (float*)nullptr, 0, 0, 0, Wadj, pool+POOL_AB3S, adj);
    hipLaunchKernelGGL(smax_h_kernel, dim3(NH), dim3(512), 0, stream, adj, wh);
    hipLaunchKernelGGL(smax_o_kernel, dim3(NB), dim3(64), 0, stream, adj, wo);

    // O-path -> h update
    launch_mfma<0,0,float>(stream, NB, EDIM, EDIM, EDIM, EDIM, 1,
        oBb, O1T, pool+POOL_OB1, aoO, EDIM, 0, 0, nullptr, nullptr, nullptr);
    hipLaunchKernelGGL(wredH_kernel, dim3(NH,8), dim3(128), 0, stream,
                       wh, aoO, s4, 1024, mwH);
    launch_mfma<0,0,float>(stream, 128, EDIM, EDIM, EDIM, EDIM, 1,
        mwH, O3T, nullptr, hmsg, EDIM, 0, 0, nullptr, nullptr, nullptr);
    hipLaunchKernelGGL(ln_update_kernel, dim3(NH), dim3(1024), 0, stream,
                       hmsg, pool+POOL_OB3S, gh, bh, hB, hBb);

    // S-path -> o update (uses updated h)
    launch_mfma<0,0,float>(stream, 128, EDIM, EDIM, EDIM, EDIM, 1,
        hBb, S1T, pool+POOL_SB1, ahS, EDIM, 0, 0, nullptr, nullptr, nullptr);
    hipLaunchKernelGGL(wredO_kernel, dim3(NB,8), dim3(128), 0, stream,
                       wo, ahS, s4, 2048, mwO);
    launch_mfma<0,0,float>(stream, NB, EDIM, EDIM, EDIM, EDIM, 1,
        mwO, S3T, nullptr, omsg, EDIM, 0, 0, nullptr, nullptr, nullptr);
    hipLaunchKernelGGL(ln_update_kernel, dim3(NB), dim3(1024), 0, stream,
                       omsg, pool+POOL_SB3S, go, bo, oB, oBb);
  }

  // ---- final heads ----
  launch_mfma<0,0,float>(stream, 128, EDIM, EDIM, EDIM, 2048, 1,
      hBb, A1T, pool+POOL_AB1, ahA, EDIM, 0, 0, nullptr, nullptr, nullptr);
  launch_mfma<0,0,float>(stream, NB, EDIM, EDIM, EDIM, 2048, 1,
      oBb, A1T+1024, nullptr, aoA, EDIM, 0, 0, nullptr, nullptr, nullptr);
  hipLaunchKernelGGL(mmake_kernel, dim3(PAIRS), dim3(256), 0, stream,
                     ahA, 1, 1024, aoA, 1, s4, 4096, 0, mbuf);
  launch_mfma<0,1,out_t>(stream, PAIRS, EDIM, EDIM, EDIM, EDIM, 1,
      mbuf, A3T, pool+POOL_AB3S, out, 2048, 0, 0, nullptr, nullptr, nullptr);

  hipLaunchKernelGGL(mmake_kernel, dim3(PAIRS), dim3(256), 0, stream,
                     aGv, 1, 0, nullptr, 0, s4, 4096, 3072, mbuf);
  launch_mfma<0,1,out_t>(stream, PAIRS, EDIM, EDIM, EDIM, EDIM, 1,
      mbuf, G3T, pool+POOL_GB3S, out, 2048, 1024, 0, nullptr, nullptr, nullptr);
}